// Round 1
// baseline (218.177 us; speedup 1.0000x reference)
//
#include <hip/hip_runtime.h>

// Destroy operator: y = (U kron I2) @ x where U[i,i+1] = sqrt(i+1).
// Reduces to: out[r, :] = sqrt(r/2 + 1) * x[r+2, :] for r < 2D-2; last 2 rows = 0.
// x: (2D, B) fp32 row-major, D = 4096, B = 4096.
//
// Pure memory-bound shift-and-scale. float4 vectorized, one thread per 4 floats.
// B/4 = 1024 float4 per row -> row = idx >> 10 (wave-uniform within a row,
// so the coefficient sqrt is effectively scalar and branch is uniform except
// at the 2-row zero tail).

constexpr int kD = 4096;
constexpr int kB = 4096;
constexpr int kRows = 2 * kD;            // 8192
constexpr int kVecPerRow = kB / 4;       // 1024
constexpr int kN4 = kRows * kVecPerRow;  // 8,388,608 float4 elements
constexpr int kShift4 = 2 * kVecPerRow;  // shift of 2 rows in float4 units

__global__ __launch_bounds__(256) void destroy_kernel(
    const float4* __restrict__ x, float4* __restrict__ y) {
    int i = blockIdx.x * blockDim.x + threadIdx.x;
    if (i >= kN4) return;

    int row = i >> 10;  // i / kVecPerRow
    if (row >= kRows - 2) {
        y[i] = make_float4(0.f, 0.f, 0.f, 0.f);
        return;
    }
    float c = sqrtf((float)((row >> 1) + 1));
    float4 v = x[i + kShift4];
    y[i] = make_float4(c * v.x, c * v.y, c * v.z, c * v.w);
}

extern "C" void kernel_launch(void* const* d_in, const int* in_sizes, int n_in,
                              void* d_out, int out_size, void* d_ws, size_t ws_size,
                              hipStream_t stream) {
    const float4* x = (const float4*)d_in[0];
    float4* y = (float4*)d_out;
    dim3 block(256);
    dim3 grid((kN4 + 255) / 256);  // 32768 blocks
    destroy_kernel<<<grid, block, 0, stream>>>(x, y);
}